// Round 13
// baseline (175.748 us; speedup 1.0000x reference)
//
#include <hip/hip_runtime.h>

// ---------------- types / helpers ----------------
typedef unsigned short u16;
typedef float f32x4 __attribute__((ext_vector_type(4)));
typedef short bf16x8 __attribute__((ext_vector_type(8)));
typedef short bf16x4 __attribute__((ext_vector_type(4)));

__device__ __forceinline__ u16 f2bf(float f) {
    unsigned u = __float_as_uint(f);
    u = (u + 0x7FFFu + ((u >> 16) & 1u)) >> 16;
    return (u16)u;
}

#define LOG2E 1.4426950408889634f

#if __has_builtin(__builtin_amdgcn_exp2f)
__device__ __forceinline__ float exp2_fast(float x) { return __builtin_amdgcn_exp2f(x); }
#else
__device__ __forceinline__ float exp2_fast(float x) { return __expf(x * 0.6931471805599453f); }
#endif

__device__ __forceinline__ unsigned pack2bf(float a, float b) {
    unsigned ua = __float_as_uint(a) + 0x8000u;
    unsigned ub = __float_as_uint(b) + 0x8000u;
#if __has_builtin(__builtin_amdgcn_perm)
    return __builtin_amdgcn_perm(ub, ua, 0x07060302u);
#else
    return ((ua >> 16) & 0xFFFFu) | (ub & 0xFFFF0000u);
#endif
}

#if __has_builtin(__builtin_amdgcn_cvt_pk_bf16_f32)
typedef __bf16 bf2_t __attribute__((ext_vector_type(2)));
__device__ __forceinline__ unsigned cvtpk(float a, float b) {
    bf2_t r = __builtin_amdgcn_cvt_pk_bf16_f32(a, b);
    return __builtin_bit_cast(unsigned, r);
}
#else
__device__ __forceinline__ unsigned cvtpk(float a, float b) { return pack2bf(a, b); }
#endif

__device__ __forceinline__ bf16x4 bc4(uint2 u) { return __builtin_bit_cast(bf16x4, u); }
__device__ __forceinline__ bf16x8 bc8(uint4 u) { return __builtin_bit_cast(bf16x8, u); }

// PV MFMA: 16x16x16 bf16. A[m=lane&15][k=quad*4+j], B[k=quad*4+j][n=lane&15].
#if __has_builtin(__builtin_amdgcn_mfma_f32_16x16x16bf16_1k)
__device__ __forceinline__ f32x4 pv_mfma(bf16x4 a, bf16x4 b, f32x4 c) {
    return __builtin_amdgcn_mfma_f32_16x16x16bf16_1k(a, b, c, 0, 0, 0);
}
#elif __has_builtin(__builtin_amdgcn_mfma_f32_16x16x16_bf16)
__device__ __forceinline__ f32x4 pv_mfma(bf16x4 a, bf16x4 b, f32x4 c) {
    return __builtin_amdgcn_mfma_f32_16x16x16_bf16(a, b, c, 0, 0, 0);
}
#else
__device__ __forceinline__ f32x4 pv_mfma(bf16x4 a, bf16x4 b, f32x4 c) {
    bf16x8 a8 = {a[0], a[1], a[2], a[3], 0, 0, 0, 0};
    bf16x8 b8 = {b[0], b[1], b[2], b[3], 0, 0, 0, 0};
    return __builtin_amdgcn_mfma_f32_16x16x32_bf16(a8, b8, c, 0, 0, 0);
}
#endif

// Problem constants
#define BB 2
#define HH 56
#define CC 256
#define NH 8
#define DK 32
#define SQ 3136
#define HP 62
#define SK 3844
#define NTG 241           // key16-tiles per (b,h): ceil(3844/16)

// workspace offsets (u16 units); total 5,648,384 u16 = 11.3 MB
#define WS_Q    0         // 6272*256
#define WS_K    1605632   // 7688*256
#define WS_V3   3573760   // 2*8*241*512 = 1,974,272
#define WS_LB   5548032   // 50176 floats

#define NZERO_F4 413952   // (6272*256 + 6272*8)/4 float4 slots

// ---------------- kernel 1: projections (+ zero out/lbuf for attn atomics) ----------------
// grid (121, 3 modes, 2 n-halves). mode: 0=Q (M=6272), 1=K, 2=V (tiled V3 layout).
// V3: [b][h][tg 0..240][dk 0..31][key16]  -> attn V loads are 512B-contiguous per wave.
#define BSTR 40
__global__ __launch_bounds__(256, 4) void proj_kernel(const float* __restrict__ x,
                                                      const float* __restrict__ Wq,
                                                      const float* __restrict__ Wk,
                                                      const float* __restrict__ Wv,
                                                      const float* __restrict__ bq,
                                                      const float* __restrict__ bk,
                                                      const float* __restrict__ bv,
                                                      u16* __restrict__ qout,
                                                      u16* __restrict__ kout,
                                                      u16* __restrict__ v3out,
                                                      float* __restrict__ out,
                                                      float* __restrict__ lbuf) {
    __shared__ __align__(16) u16 Bl[128 * BSTR];

    int mode  = blockIdx.y;
    int nz    = blockIdx.z;
    int mbase = blockIdx.x * 64;
    int tid = threadIdx.x;

    // zero out + lbuf across all 726 blocks, float4
    {
        int gid = ((blockIdx.z * 3 + blockIdx.y) * 121 + blockIdx.x) * 256 + tid;
        const int n_out4 = (SQ * BB * CC) / 4;
        for (int i = gid; i < NZERO_F4; i += 726 * 256) {
            if (i < n_out4) *(float4*)&out[i * 4] = (float4){0.f, 0.f, 0.f, 0.f};
            else            *(float4*)&lbuf[(i - n_out4) * 4] = (float4){0.f, 0.f, 0.f, 0.f};
        }
    }

    int M = (mode == 0) ? (BB * SQ) : (BB * SK);
    if (mbase >= M) return;
    int wave = tid >> 6, lane = tid & 63, quad = lane >> 4, l16 = lane & 15;

    const float* W = (mode == 0) ? Wq : ((mode == 1) ? Wk : Wv);
    const float* bias = (mode == 0) ? bq : ((mode == 1) ? bk : bv);
    float wscale = (mode == 0) ? LOG2E : 1.0f;

    int m_a = mbase + wave * 16 + l16;
    if (m_a >= M) m_a = M - 1;
    int xrow;
    if (mode == 0) {
        xrow = m_a;
    } else {
        int b = (m_a >= SK) ? 1 : 0;
        int sp = m_a - b * SK;
        int hp = sp / HP, wp = sp - hp * HP;
        int hs = hp - 3; hs = hs < 0 ? -hs : (hs >= HH ? 110 - hs : hs);
        int ws_ = wp - 3; ws_ = ws_ < 0 ? -ws_ : (ws_ >= HH ? 110 - ws_ : ws_);
        xrow = b * SQ + hs * HH + ws_;
    }
    const float* xr = x + (size_t)xrow * 256;

    int kq = tid >> 3;          // k-row 0..31
    int cb = (tid & 7) * 16;    // col base

    f32x4 acc[8];
#pragma unroll
    for (int i = 0; i < 8; i++) acc[i] = (f32x4){0.f, 0.f, 0.f, 0.f};

    float4 wreg[4];
    auto wload = [&](int s) {
        const float* p = W + (size_t)(s * 32 + kq) * 256 + nz * 128 + cb;
        wreg[0] = *(const float4*)&p[0];
        wreg[1] = *(const float4*)&p[4];
        wreg[2] = *(const float4*)&p[8];
        wreg[3] = *(const float4*)&p[12];
    };

    wload(0);
    for (int s = 0; s < 8; ++s) {
        int kk = s * 32;
#pragma unroll
        for (int i = 0; i < 16; i++) {
            float v = ((const float*)wreg)[i] * wscale;
            Bl[(cb + i) * BSTR + kq] = f2bf(v);
        }
        __syncthreads();
        if (s < 7) wload(s + 1);
        float4 f0 = *(const float4*)&xr[kk + quad * 8];
        float4 f1 = *(const float4*)&xr[kk + quad * 8 + 4];
        uint4 aw = (uint4){pack2bf(f0.x, f0.y), pack2bf(f0.z, f0.w),
                           pack2bf(f1.x, f1.y), pack2bf(f1.z, f1.w)};
        bf16x8 afrag = bc8(aw);
#pragma unroll
        for (int nt = 0; nt < 8; nt++) {
            bf16x8 bfrag = *(const bf16x8*)&Bl[(nt * 16 + l16) * BSTR + quad * 8];
            acc[nt] = __builtin_amdgcn_mfma_f32_16x16x32_bf16(afrag, bfrag, acc[nt], 0, 0, 0);
        }
        __syncthreads();
    }

    int mrow_base = mbase + wave * 16 + quad * 4;
    if (mode == 2) {
        // V3 tiled store: c -> (h = c>>5, dk32 = c&31); pair (kp, kp+1) same tile (kp even)
#pragma unroll
        for (int nt = 0; nt < 8; nt++) {
            int c = nz * 128 + nt * 16 + l16;
            int hh = c >> 5, dk32 = c & 31;
            float bvv = bias[c];
#pragma unroll
            for (int p = 0; p < 4; p += 2) {
                int m = mrow_base + p;
                if (m + 1 < M) {
                    int bb = (m >= SK) ? 1 : 0;
                    int kp = m - bb * SK;
                    int tg = kp >> 4, ki = kp & 15;
                    unsigned pk = pack2bf(acc[nt][p] + bvv, acc[nt][p + 1] + bvv);
                    size_t addr = ((size_t)((bb * 8 + hh) * NTG + tg) << 9) + dk32 * 16 + ki;
                    *(unsigned*)&v3out[addr] = pk;
                }
            }
        }
    } else {
#pragma unroll
        for (int r = 0; r < 4; r++) {
            int m = mrow_base + r;
            if (m >= M) continue;
#pragma unroll
            for (int nt = 0; nt < 8; nt++) {
                int c = nz * 128 + nt * 16 + l16;
                float v = acc[nt][r] + bias[c] * ((mode == 0) ? LOG2E : 1.0f);
                u16 hv = f2bf(v);
                if (mode == 0) qout[((size_t)m << 8) + c] = hv;
                else           kout[((size_t)m << 8) + c] = hv;
            }
        }
    }
}

// ---------------- kernel 2: flash attention (fixed m=0), NO-LDS streaming ----------------
// grid (49, 16, 2 key-halves), 256 thr = 4 waves. wave w: qs=w&1 -> 32 queries;
// th=w>>1 -> key-tile quarter (4 key16-tiles per 128-chunk). Each wave streams its own
// K (row-major, 64B-coalesced) and V3 (512B-contiguous) straight to registers:
// keys are partitioned across waves -> LDS staging had zero reuse, so none is used.
// No barriers in the main loop. 1-chunk prefetch in named regs. 12KB LDS merge at end.
__global__ __launch_bounds__(256) void attn_kernel(const u16* __restrict__ qb,
                                                   const u16* __restrict__ kb,
                                                   const u16* __restrict__ v3b,
                                                   float* __restrict__ out,
                                                   float* __restrict__ lbuf) {
    __shared__ __align__(16) float mg[3072];   // 12KB merge scratch

    int tid = threadIdx.x;
    int wave = tid >> 6, lane = tid & 63, quad = lane >> 4, l16 = lane & 15;
    int qs = wave & 1, th = wave >> 1;
    int bh = blockIdx.y;
    int b = bh >> 3, h = bh & 7;
    int half = blockIdx.z;
    int qsub = blockIdx.x * 64 + qs * 32;
    int rounds = half ? 15 : 16;              // chunks half*16 + r (31 total)
    int ch0 = half * 16;

    // Q B-fragments (16x16x32): n=l16 -> query, k=quad*8+j
    bf16x8 qf0 = *(const bf16x8*)&qb[((size_t)(b * SQ + qsub + l16) << 8) + h * 32 + quad * 8];
    bf16x8 qf1 = *(const bf16x8*)&qb[((size_t)(b * SQ + qsub + 16 + l16) << 8) + h * 32 + quad * 8];

    const u16* kg  = kb + ((size_t)(b * SK) << 8) + h * 32;
    const u16* vgp = v3b + ((size_t)((b * 8 + h) * NTG) << 9);

    f32x4 o00{0.f,0.f,0.f,0.f}, o01{0.f,0.f,0.f,0.f};
    f32x4 o10{0.f,0.f,0.f,0.f}, o11{0.f,0.f,0.f,0.f};
    f32x4 l0{0.f,0.f,0.f,0.f},  l1{0.f,0.f,0.f,0.f};

    short ov = (l16 == 0) ? (short)0x3F80 : (short)0;
    bf16x4 ones4 = {ov, ov, ov, ov};

    // per-chunk loads (wave-private): 4 key16-tiles tg = ch*8 + th*4 + tt
    auto kptr = [&](int ch, int tt) -> const uint4* {
        int key = (ch * 8 + th * 4 + tt) * 16 + l16;
        if (key > SK - 1) key = SK - 1;
        return (const uint4*)&kg[((size_t)key << 8) + quad * 8];
    };
    auto vptr = [&](int ch, int tt, int hi) -> const uint2* {
        int tg = ch * 8 + th * 4 + tt;
        if (tg > NTG - 1) tg = NTG - 1;
        return (const uint2*)&vgp[((size_t)tg << 9) + hi * 256 + l16 * 16 + quad * 4];
    };

    // named prefetch registers (two sets, rotated) — no arrays across latency
    uint4 kA0, kA1, kA2, kA3, kB0, kB1, kB2, kB3;
    uint2 vA0l, vA0h, vA1l, vA1h, vA2l, vA2h, vA3l, vA3h;
    uint2 vB0l, vB0h, vB1l, vB1h, vB2l, vB2h, vB3l, vB3h;

    auto loadA = [&](int ch) {
        kA0 = *kptr(ch, 0); kA1 = *kptr(ch, 1); kA2 = *kptr(ch, 2); kA3 = *kptr(ch, 3);
        vA0l = *vptr(ch, 0, 0); vA0h = *vptr(ch, 0, 1);
        vA1l = *vptr(ch, 1, 0); vA1h = *vptr(ch, 1, 1);
        vA2l = *vptr(ch, 2, 0); vA2h = *vptr(ch, 2, 1);
        vA3l = *vptr(ch, 3, 0); vA3h = *vptr(ch, 3, 1);
    };
    auto loadB = [&](int ch) {
        kB0 = *kptr(ch, 0); kB1 = *kptr(ch, 1); kB2 = *kptr(ch, 2); kB3 = *kptr(ch, 3);
        vB0l = *vptr(ch, 0, 0); vB0h = *vptr(ch, 0, 1);
        vB1l = *vptr(ch, 1, 0); vB1h = *vptr(ch, 1, 1);
        vB2l = *vptr(ch, 2, 0); vB2h = *vptr(ch, 2, 1);
        vB3l = *vptr(ch, 3, 0); vB3h = *vptr(ch, 3, 1);
    };

    auto compute_tt = [&](int ch, int tt, uint4 kreg, uint2 vlo, uint2 vhi) {
        bf16x8 kf = bc8(kreg);
        f32x4 e0 = __builtin_amdgcn_mfma_f32_16x16x32_bf16(kf, qf0, (f32x4){0.f,0.f,0.f,0.f}, 0, 0, 0);
        f32x4 e1 = __builtin_amdgcn_mfma_f32_16x16x32_bf16(kf, qf1, (f32x4){0.f,0.f,0.f,0.f}, 0, 0, 0);
        bf16x4 pa0, pa1;
        if (ch == 30) {
            int kb0 = (ch * 8 + th * 4 + tt) * 16 + quad * 4;
            float p00 = (kb0 + 0) < SK ? exp2_fast(e0[0]) : 0.f;
            float p01 = (kb0 + 1) < SK ? exp2_fast(e0[1]) : 0.f;
            float p02 = (kb0 + 2) < SK ? exp2_fast(e0[2]) : 0.f;
            float p03 = (kb0 + 3) < SK ? exp2_fast(e0[3]) : 0.f;
            float p10 = (kb0 + 0) < SK ? exp2_fast(e1[0]) : 0.f;
            float p11 = (kb0 + 1) < SK ? exp2_fast(e1[1]) : 0.f;
            float p12 = (kb0 + 2) < SK ? exp2_fast(e1[2]) : 0.f;
            float p13 = (kb0 + 3) < SK ? exp2_fast(e1[3]) : 0.f;
            pa0 = bc4((uint2){cvtpk(p00, p01), cvtpk(p02, p03)});
            pa1 = bc4((uint2){cvtpk(p10, p11), cvtpk(p12, p13)});
        } else {
            pa0 = bc4((uint2){cvtpk(exp2_fast(e0[0]), exp2_fast(e0[1])),
                              cvtpk(exp2_fast(e0[2]), exp2_fast(e0[3]))});
            pa1 = bc4((uint2){cvtpk(exp2_fast(e1[0]), exp2_fast(e1[1])),
                              cvtpk(exp2_fast(e1[2]), exp2_fast(e1[3]))});
        }
        bf16x4 vb0 = bc4(vlo), vb1 = bc4(vhi);
        o00 = pv_mfma(pa0, vb0, o00);
        o01 = pv_mfma(pa0, vb1, o01);
        o10 = pv_mfma(pa1, vb0, o10);
        o11 = pv_mfma(pa1, vb1, o11);
        l0  = pv_mfma(pa0, ones4, l0);
        l1  = pv_mfma(pa1, ones4, l1);
    };

    auto computeA = [&](int ch) {
        compute_tt(ch, 0, kA0, vA0l, vA0h);
        compute_tt(ch, 1, kA1, vA1l, vA1h);
        compute_tt(ch, 2, kA2, vA2l, vA2h);
        compute_tt(ch, 3, kA3, vA3l, vA3h);
    };
    auto computeB = [&](int ch) {
        compute_tt(ch, 0, kB0, vB0l, vB0h);
        compute_tt(ch, 1, kB1, vB1l, vB1h);
        compute_tt(ch, 2, kB2, vB2l, vB2h);
        compute_tt(ch, 3, kB3, vB3l, vB3h);
    };

    loadA(ch0);
    for (int r = 0; r < rounds; r += 2) {
        if (r + 1 < rounds) loadB(ch0 + r + 1);
        computeA(ch0 + r);
        if (r + 1 >= rounds) break;
        if (r + 2 < rounds) loadA(ch0 + r + 2);
        computeB(ch0 + r + 1);
    }

    // ---- merge t-halves via LDS (th=1 -> th=0), then 2-way cross-block atomics ----
    int slot = (qs * 64 + lane) * 24;
    if (th == 1) {
        *(f32x4*)&mg[slot + 0]  = o00;
        *(f32x4*)&mg[slot + 4]  = o01;
        *(f32x4*)&mg[slot + 8]  = o10;
        *(f32x4*)&mg[slot + 12] = o11;
        *(f32x4*)&mg[slot + 16] = l0;
        *(f32x4*)&mg[slot + 20] = l1;
    }
    __syncthreads();
    if (th == 0) {
        o00 += *(const f32x4*)&mg[slot + 0];
        o01 += *(const f32x4*)&mg[slot + 4];
        o10 += *(const f32x4*)&mg[slot + 8];
        o11 += *(const f32x4*)&mg[slot + 12];
        l0  += *(const f32x4*)&mg[slot + 16];
        l1  += *(const f32x4*)&mg[slot + 20];

#pragma unroll
        for (int r2 = 0; r2 < 4; ++r2) {
            int q0 = qsub + quad * 4 + r2;
            int q1 = q0 + 16;
            size_t base0 = (size_t)(b * SQ + q0) * 256 + h * 32;
            size_t base1 = (size_t)(b * SQ + q1) * 256 + h * 32;
            atomicAdd(&out[base0 + l16],      o00[r2]);
            atomicAdd(&out[base0 + 16 + l16], o01[r2]);
            atomicAdd(&out[base1 + l16],      o10[r2]);
            atomicAdd(&out[base1 + 16 + l16], o11[r2]);
            if (l16 == 0) {
                atomicAdd(&lbuf[(b * SQ + q0) * 8 + h], l0[r2]);
                atomicAdd(&lbuf[(b * SQ + q1) * 8 + h], l1[r2]);
            }
        }
    }
}

// ---------------- kernel 3: finalize out = gamma * O / l + x ----------------
__global__ __launch_bounds__(256) void finalize_kernel(const float* __restrict__ x,
                                                       const float* __restrict__ gammap,
                                                       const float* __restrict__ lbuf,
                                                       float* __restrict__ out) {
    int gid = blockIdx.x * 256 + threadIdx.x;   // 6272*64 threads, float4 each
    int row = gid >> 6;
    int c4  = (gid & 63) << 2;
    int h   = c4 >> 5;
    float g = gammap[0];
    float linv = g / lbuf[row * 8 + h];
    size_t base = (size_t)row * 256 + c4;
    float4 o = *(const float4*)&out[base];
    float4 xv = *(const float4*)&x[base];
    o.x = o.x * linv + xv.x;
    o.y = o.y * linv + xv.y;
    o.z = o.z * linv + xv.z;
    o.w = o.w * linv + xv.w;
    *(float4*)&out[base] = o;
}

// ---------------- launcher ----------------
extern "C" void kernel_launch(void* const* d_in, const int* in_sizes, int n_in,
                              void* d_out, int out_size, void* d_ws, size_t ws_size,
                              hipStream_t stream) {
    const float* x     = (const float*)d_in[0];
    const float* Wq    = (const float*)d_in[1];
    const float* bq    = (const float*)d_in[2];
    const float* Wk    = (const float*)d_in[3];
    const float* bk    = (const float*)d_in[4];
    const float* Wv    = (const float*)d_in[5];
    const float* bv    = (const float*)d_in[6];
    const float* gamma = (const float*)d_in[7];
    float* out = (float*)d_out;

    u16* ws   = (u16*)d_ws;
    u16* qbuf = ws + WS_Q;
    u16* kbuf = ws + WS_K;
    u16* v3b  = ws + WS_V3;
    float* lbuf = (float*)(ws + WS_LB);

    proj_kernel<<<dim3(121, 3, 2), 256, 0, stream>>>(x, Wq, Wk, Wv, bq, bk, bv,
                                                     qbuf, kbuf, v3b, out, lbuf);
    attn_kernel<<<dim3(49, 16, 2), 256, 0, stream>>>(qbuf, kbuf, v3b, out, lbuf);
    finalize_kernel<<<1568, 256, 0, stream>>>(x, gamma, lbuf, out);
}